// Round 4
// baseline (154.493 us; speedup 1.0000x reference)
//
#include <hip/hip_runtime.h>
#include <math.h>

#define S 128
#define NB 16
constexpr float STEP = 6.283185307179586f / 128.0f;   // 2*pi/128

typedef float f32x4 __attribute__((ext_vector_type(4)));  // clang vector: NT-store OK

// Kernel 1: F[b,y,s] = sum_v x[b,y,v] e^{-2pi i s v/S}, stored TRANSPOSED:
//   Ft[(b*S + s)*S + y]
// block = (b,y), 128 threads (thread = s). Twiddles in a float2 LDS table.
__global__ void dft_rows(const float* __restrict__ in, float2* __restrict__ Ft) {
    const int by = blockIdx.x;
    const int b  = by >> 7;
    const int y  = by & (S - 1);
    const int s  = threadIdx.x;

    __shared__ float  row[S];
    __shared__ float2 tw[S];                  // (cos, sin)
    row[s] = in[((b * 2 + 0) * S + y) * S + s];
    float sn, cs;
    __sincosf((float)s * STEP, &sn, &cs);
    tw[s] = make_float2(cs, sn);
    __syncthreads();

    float re = 0.f, im = 0.f;
#pragma unroll 8
    for (int v = 0; v < S; ++v) {
        const int k = (s * v) & (S - 1);
        const float2 t = tw[k];
        const float xv = row[v];              // LDS broadcast
        re = fmaf(xv,  t.x, re);
        im = fmaf(xv, -t.y, im);
    }
    Ft[(b * S + s) * S + y] = make_float2(re, im);
}

// Kernel 2: blocks 0..2047: (b,s) tile — writes a contiguous 64 KiB image:
//   out[((b*129 + s)*S + y)*S + x] = (1/S)(Fre*cos(2pi s x/S) - Fim*sin(2pi s x/S))
// blocks 2048..2063: copy channel 1 of batch b to out channel 128.
// All output stores nontemporal (streaming, never re-read).
__global__ void modulate(const float2* __restrict__ Ft, const float* __restrict__ in,
                         float* __restrict__ out) {
    const int blk = blockIdx.x;
    const int t   = threadIdx.x;              // 0..255

    if (blk >= NB * S) {                      // passthrough blocks (uniform branch)
        const int b = blk - NB * S;
        const f32x4* src = (const f32x4*)&in[((b * 2 + 1) * S) * S];
        f32x4*       dst = (f32x4*)&out[((b * 129 + S) * S) * S];
#pragma unroll
        for (int i = 0; i < 16; ++i) {
            const f32x4 v = src[i * 256 + t];
            __builtin_nontemporal_store(v, &dst[i * 256 + t]);
        }
        return;
    }

    const int b = blk >> 7;
    const int s = blk & (S - 1);

    __shared__ float2 Fs[S];                  // F[b, y, s] for all y
    __shared__ float  cosT[S], sinT[S];
    if (t < S) {
        Fs[t] = Ft[(b * S + s) * S + t];      // contiguous 1 KiB
        float sn, cs;
        __sincosf((float)t * STEP, &sn, &cs);
        cosT[t] = cs;
        sinT[t] = sn;
    }
    __syncthreads();

    const int x0 = (t & 31) * 4;              // this thread's 4 x values
    const int y0 = t >> 5;                    // 0..7, y advances by 8

    float mc[4], ms[4];                       // modulation factors, registers
#pragma unroll
    for (int j = 0; j < 4; ++j) {
        const int k = (s * (x0 + j)) & (S - 1);
        mc[j] = cosT[k];
        ms[j] = sinT[k];
    }

    // Prefetch all 16 F values into registers: one lgkm drain, then the 16
    // FMA+store groups issue back-to-back with no interleaved LDS waits.
    float2 fv[16];
#pragma unroll
    for (int i = 0; i < 16; ++i)
        fv[i] = Fs[y0 + i * 8];               // 32-lane broadcast each

    float* obase = &out[((b * 129 + s) * S) * S];
#pragma unroll
    for (int i = 0; i < 16; ++i) {
        const int y = y0 + i * 8;
        const float re = fv[i].x * (1.0f / S);
        const float im = fv[i].y * (1.0f / S);
        f32x4 o;
        o.x = re * mc[0] - im * ms[0];
        o.y = re * mc[1] - im * ms[1];
        o.z = re * mc[2] - im * ms[2];
        o.w = re * mc[3] - im * ms[3];
        __builtin_nontemporal_store(o, (f32x4*)&obase[y * S + x0]);
    }
}

extern "C" void kernel_launch(void* const* d_in, const int* in_sizes, int n_in,
                              void* d_out, int out_size, void* d_ws, size_t ws_size,
                              hipStream_t stream) {
    const float* in  = (const float*)d_in[0];
    float*       out = (float*)d_out;
    float2*      Ft  = (float2*)d_ws;         // 16*128*128 float2 = 2 MiB

    dft_rows<<<NB * S, S, 0, stream>>>(in, Ft);
    modulate<<<NB * S + NB, 256, 0, stream>>>(Ft, in, out);
}

// Round 7
// 150.564 us; speedup vs baseline: 1.0261x; 1.0261x over previous
//
#include <hip/hip_runtime.h>
#include <math.h>

#define S 128
#define NB 16
#define PITCH 129                                   // 129 mod 32 = 1 -> conflict-free column access
constexpr float STEP = 6.283185307179586f / 128.0f; // 2*pi/128

typedef float f32x4 __attribute__((ext_vector_type(4)));

// One fused kernel.
// Blocks 0..511: (b, sq) with b = blk>>5, sq = blk&31; handles s = sq*4 + {0..3}.
//   Phase A: stage channel-0 image b (64 KB) into LDS, pitch 129.
//   Phase B: DFT columns F[s][y] = sum_v img[y][v] e^{-2pi i s v/128} via rotation
//            recurrence (thread = (s_local, half, y); halves split the v-range).
//   Phase C: modulate + write 4 contiguous 64 KiB output images:
//            out[b,s,y,x] = (FRe cos(2pi s x/128) - FIm sin(2pi s x/128)) / 128.
// Blocks 512..527: copy channel 1 of batch b to out channel 128.
__global__ __launch_bounds__(1024, 8)
void kspace_fused(const float* __restrict__ in, float* __restrict__ out) {
    const int blk = blockIdx.x;
    const int t   = threadIdx.x;                    // 0..1023

    if (blk >= NB * 32) {                           // passthrough (uniform branch)
        const int b = blk - NB * 32;
        const f32x4* src = (const f32x4*)&in[(b * 2 + 1) * S * S];
        f32x4*       dst = (f32x4*)&out[(b * 129 + S) * S * S];
#pragma unroll
        for (int i = 0; i < 4; ++i) {
            const f32x4 v = src[t + i * 1024];
            __builtin_nontemporal_store(v, &dst[t + i * 1024]);
        }
        return;
    }

    const int b  = blk >> 5;                        // 0..15
    const int sq = blk & 31;                        // 0..31

    __shared__ float  img[S * PITCH];               // 66,048 B
    __shared__ float2 part[4][2][S];                // 8,192 B

    // ---- Phase A: stage image (coalesced 64 KB global read, pitched LDS write)
    {
        const f32x4* src = (const f32x4*)&in[(b * 2) * S * S];
#pragma unroll
        for (int i = 0; i < 4; ++i) {
            const int fidx = t + i * 1024;          // float4 index 0..4095
            const f32x4 v = src[fidx];
            const int y = fidx >> 5;                // 32 float4 per row
            const int c = fidx & 31;
            float* p = &img[y * PITCH + c * 4];
            p[0] = v.x; p[1] = v.y; p[2] = v.z; p[3] = v.w;
        }
    }
    __syncthreads();

    // ---- Phase B: DFT by rotation recurrence (no twiddle table, no conflicts)
    const int s_local = t >> 8;                     // 0..3
    const int s       = sq * 4 + s_local;
    const int y       = t & 127;
    const int half    = (t >> 7) & 1;               // v in [64*half, 64*half+64)

    float sn1, cs1;
    __sincosf((float)s * STEP, &sn1, &cs1);         // w1 = e^{-2pi i s/128} = (cs1, -sn1)

    // w = e^{-2pi i s v0/128}: v0=0 -> 1; v0=64 -> e^{-pi i s} = (-1)^s (exact)
    float wRe = half ? ((s & 1) ? -1.f : 1.f) : 1.f;
    float wIm = 0.f;
    float accRe = 0.f, accIm = 0.f;
    const float* row = &img[y * PITCH + half * 64]; // lanes: y stride 1 -> bank stride 1
#pragma unroll 8
    for (int v = 0; v < 64; ++v) {
        const float xv = row[v];
        accRe = fmaf(xv, wRe, accRe);
        accIm = fmaf(xv, wIm, accIm);
        const float nRe = fmaf(wRe, cs1,  wIm * sn1);   // (wRe,wIm) *= (cs1,-sn1)
        const float nIm = fmaf(wIm, cs1, -wRe * sn1);
        wRe = nRe; wIm = nIm;
    }
    part[s_local][half][y] = make_float2(accRe, accIm);
    __syncthreads();

    // ---- Phase C: modulate + contiguous NT stores (1 KB per wave per iter)
    const int x0 = (t & 31) * 4;
    const int y0 = (t >> 5) & 7;

    float mc[4], ms[4];
#pragma unroll
    for (int j = 0; j < 4; ++j) {
        const int k = (s * (x0 + j)) & (S - 1);
        __sincosf((float)k * STEP, &ms[j], &mc[j]);
    }

    float* obase = &out[((b * 129 + s) * S) * S];
#pragma unroll
    for (int i = 0; i < 16; ++i) {
        const int yy = y0 + i * 8;
        const float2 p0 = part[s_local][0][yy];     // LDS broadcast
        const float2 p1 = part[s_local][1][yy];
        const float fRe = (p0.x + p1.x) * (1.0f / S);
        const float fIm = (p0.y + p1.y) * (1.0f / S);
        f32x4 o;
        o.x = fRe * mc[0] - fIm * ms[0];
        o.y = fRe * mc[1] - fIm * ms[1];
        o.z = fRe * mc[2] - fIm * ms[2];
        o.w = fRe * mc[3] - fIm * ms[3];
        __builtin_nontemporal_store(o, (f32x4*)&obase[yy * S + x0]);
    }
}

extern "C" void kernel_launch(void* const* d_in, const int* in_sizes, int n_in,
                              void* d_out, int out_size, void* d_ws, size_t ws_size,
                              hipStream_t stream) {
    const float* in  = (const float*)d_in[0];
    float*       out = (float*)d_out;
    kspace_fused<<<NB * 32 + NB, 1024, 0, stream>>>(in, out);
}

// Round 8
// 145.438 us; speedup vs baseline: 1.0623x; 1.0352x over previous
//
#include <hip/hip_runtime.h>
#include <math.h>

#define S 128
#define NB 16
constexpr float STEP = 6.283185307179586f / 128.0f;   // 2*pi/128

typedef float f32x4 __attribute__((ext_vector_type(4)));

// Kernel 1 (round-2 proven): F[b,y,s] = sum_v x[b,y,v] e^{-2pi i s v/S},
// stored TRANSPOSED: Ft[(b*S + s)*S + y]. Block = (b,y), thread = s.
__global__ void dft_rows(const float* __restrict__ in, float2* __restrict__ Ft) {
    const int by = blockIdx.x;
    const int b  = by >> 7;
    const int y  = by & (S - 1);
    const int s  = threadIdx.x;

    __shared__ float  row[S];
    __shared__ float2 tw[S];                  // (cos, sin)
    row[s] = in[((b * 2 + 0) * S + y) * S + s];
    float sn, cs;
    __sincosf((float)s * STEP, &sn, &cs);
    tw[s] = make_float2(cs, sn);
    __syncthreads();

    float re = 0.f, im = 0.f;
#pragma unroll 8
    for (int v = 0; v < S; ++v) {
        const int k = (s * v) & (S - 1);
        const float2 t = tw[k];
        const float xv = row[v];              // LDS broadcast
        re = fmaf(xv,  t.x, re);
        im = fmaf(xv, -t.y, im);
    }
    Ft[(b * S + s) * S + y] = make_float2(re, im);
}

// Kernel 2: near-pure store kernel. No LDS, no barriers, tiny preamble.
// Blocks 0..4095: (b, s, h) with b=blk>>8, s=(blk>>1)&127, h=blk&1.
//   Writes half an output image (64 rows x 128 cols = 32 KB), plain stores:
//   out[((b*129+s)*S + y)*S + x] = (FRe*cos(2pi s x/S) - FIm*sin(2pi s x/S))/S
// Blocks 4096..4127: (b,h) passthrough of channel 1 -> out channel 128.
__global__ __launch_bounds__(256)
void modulate(const float2* __restrict__ Ft, const float* __restrict__ in,
              float* __restrict__ out) {
    const int blk = blockIdx.x;
    const int t   = threadIdx.x;              // 0..255

    if (blk >= NB * S * 2) {                  // passthrough (uniform branch)
        const int idx = blk - NB * S * 2;
        const int b = idx >> 1, h = idx & 1;
        const f32x4* src = (const f32x4*)&in[(b * 2 + 1) * S * S] + h * 2048;
        f32x4*       dst = (f32x4*)&out[(b * 129 + S) * S * S] + h * 2048;
#pragma unroll
        for (int i = 0; i < 8; ++i)
            dst[t + i * 256] = src[t + i * 256];
        return;
    }

    const int b = blk >> 8;
    const int s = (blk >> 1) & (S - 1);
    const int h = blk & 1;

    const int x0 = (t & 31) * 4;              // 4 contiguous x per thread
    const int yb = h * 64 + (t >> 5) * 8;     // this thread's 8 consecutive y

    // 8 F values (64 B contiguous, L2-hot) via 4 float4 loads
    union { f32x4 q[4]; float2 v[8]; } F;
    const f32x4* Fp = (const f32x4*)&Ft[(b * S + s) * S + yb];
#pragma unroll
    for (int i = 0; i < 4; ++i) F.q[i] = Fp[i];

    float mc[4], ms[4];                       // modulation factors (native sincos)
#pragma unroll
    for (int j = 0; j < 4; ++j) {
        const int k = (s * (x0 + j)) & (S - 1);
        __sincosf((float)k * STEP, &ms[j], &mc[j]);
    }

    float* obase = &out[((b * 129 + s) * S) * S];
#pragma unroll
    for (int i = 0; i < 8; ++i) {
        const float re = F.v[i].x * (1.0f / S);
        const float im = F.v[i].y * (1.0f / S);
        f32x4 o;
        o.x = re * mc[0] - im * ms[0];
        o.y = re * mc[1] - im * ms[1];
        o.z = re * mc[2] - im * ms[2];
        o.w = re * mc[3] - im * ms[3];
        *(f32x4*)&obase[(yb + i) * S + x0] = o;   // plain coalesced dwordx4
    }
}

extern "C" void kernel_launch(void* const* d_in, const int* in_sizes, int n_in,
                              void* d_out, int out_size, void* d_ws, size_t ws_size,
                              hipStream_t stream) {
    const float* in  = (const float*)d_in[0];
    float*       out = (float*)d_out;
    float2*      Ft  = (float2*)d_ws;         // 16*128*128 float2 = 2 MiB

    dft_rows<<<NB * S, S, 0, stream>>>(in, Ft);
    modulate<<<NB * S * 2 + NB * 2, 256, 0, stream>>>(Ft, in, out);
}